// Round 3
// baseline (14919.881 us; speedup 1.0000x reference)
//
#include <hip/hip_runtime.h>
#include <cstdint>

// BISECT ROUND: pure-f32 VALU EA-LSTM — no MFMA, no bf16, no d_ws.
// Same decomposition (32 WGs x 16 batch rows), same gate/elementwise/store
// code paths as the MFMA version. Isolates {gate logic, indexing, ref match}
// from {MFMA layout, bf16 numerics, pack_w/ws corruption}.

#define BN 512
#define TT 365
#define DD 16
#define DS 32
#define HH 256
#define G3 768
#define BB 16
#define KK 272          // h(256) + x(16)
#define KT 16           // k-tile staged in LDS
#define NTILE 17        // 272/16
#define AFS 280         // Af row stride (f32), 272+8 pad

__global__ __launch_bounds__(512) void ealstm_f32(
    const float* __restrict__ x_d, const float* __restrict__ x_s,
    const float* __restrict__ w_ih, const float* __restrict__ w_hh,
    const float* __restrict__ w_sh, const float* __restrict__ bias,
    const float* __restrict__ bias_s, const float* __restrict__ fc_w,
    const float* __restrict__ fc_b,
    float* __restrict__ out, float* __restrict__ h_n, float* __restrict__ c_n)
{
    __shared__ float Af[BB * AFS];      // [16][280]: k 0..255 = h, 256..271 = x_t
    __shared__ float Wl[KT * G3];       // [16][768] staged weight k-tile
    __shared__ float G[BB * G3];        // [16][768] gate preactivations

    const int tid = threadIdx.x;
    const int B0  = blockIdx.x * BB;
    const int rg  = tid >> 7;           // row group 0..3 -> rows 4rg..4rg+3
    const int ct  = tid & 127;          // col thread -> cols ct + 128*jj, jj<6

    float biasv[6];
#pragma unroll
    for (int jj = 0; jj < 6; ++jj) biasv[jj] = bias[ct + 128*jj];

    // per-thread elementwise state: flat = tid + 512*u -> b = flat>>8, j = flat&255
    float c0[8], ig[8];
#pragma unroll
    for (int u = 0; u < 8; ++u) {
        int flat = tid + 512*u;
        int b = flat >> 8, j = flat & 255;
        float a = bias_s[j];
        for (int d = 0; d < DS; ++d)
            a += x_s[(B0 + b)*DS + d] * w_sh[d*HH + j];
        ig[u] = 1.f/(1.f + __expf(-a));
        c0[u] = 0.f;
    }

    // init Af: h=0, load x_0
    for (int idx = tid; idx < BB*AFS; idx += 512) Af[idx] = 0.f;
    __syncthreads();
    if (tid < 256) {
        int b = tid >> 4, d = tid & 15;
        Af[b*AFS + HH + d] = x_d[((size_t)(B0+b)*TT + 0)*DD + d];
    }
    __syncthreads();

    for (int t = 0; t < TT; ++t) {
        // ---- gates = bias + [h|x] @ [w_hh; w_ih]  (f32, register 4x6 tile) ----
        float acc[4][6];
#pragma unroll
        for (int q = 0; q < 4; ++q)
#pragma unroll
            for (int jj = 0; jj < 6; ++jj) acc[q][jj] = biasv[jj];

        for (int kt = 0; kt < NTILE; ++kt) {
            // stage Wl[kk][j] = W_cat[kt*16+kk][j]
#pragma unroll
            for (int it = 0; it < (KT*G3)/512; ++it) {   // 24 iters
                int idx = tid + 512*it;
                int kk = idx / G3, jx = idx - kk*G3;
                int k = kt*KT + kk;
                Wl[idx] = (k < HH) ? w_hh[(size_t)k*G3 + jx]
                                   : w_ih[(size_t)(k-HH)*G3 + jx];
            }
            __syncthreads();
#pragma unroll
            for (int kk = 0; kk < KT; ++kk) {
                float af[4], wv[6];
#pragma unroll
                for (int q = 0; q < 4; ++q) af[q] = Af[(4*rg+q)*AFS + kt*KT + kk];
#pragma unroll
                for (int jj = 0; jj < 6; ++jj) wv[jj] = Wl[kk*G3 + ct + 128*jj];
#pragma unroll
                for (int q = 0; q < 4; ++q)
#pragma unroll
                    for (int jj = 0; jj < 6; ++jj)
                        acc[q][jj] += af[q]*wv[jj];
            }
            __syncthreads();   // protect Wl before next stage
        }

        // ---- exchange gate preacts through LDS ----
#pragma unroll
        for (int q = 0; q < 4; ++q)
#pragma unroll
            for (int jj = 0; jj < 6; ++jj)
                G[(4*rg+q)*G3 + ct + 128*jj] = acc[q][jj];
        __syncthreads();

        // ---- elementwise (8 states per thread) ----
#pragma unroll
        for (int u = 0; u < 8; ++u) {
            int flat = tid + 512*u;
            int b = flat >> 8, j = flat & 255;
            float f = G[b*G3 + j];
            float o = G[b*G3 + 256 + j];
            float g = G[b*G3 + 512 + j];
            float fg = 1.f/(1.f + __expf(-f));
            float og = 1.f/(1.f + __expf(-o));
            float e2g = __expf(2.f*g);
            float gg = 1.f - 2.f/(e2g + 1.f);          // tanh(g)
            float c = fg*c0[u] + ig[u]*gg;
            c0[u] = c;
            float e2c = __expf(2.f*c);
            float th = 1.f - 2.f/(e2c + 1.f);          // tanh(c), saturates to +-1
            float h = og*th;
            Af[b*AFS + j] = h;
            size_t oi = ((size_t)(B0+b)*TT + t)*HH + j;
            h_n[oi] = h;
            c_n[oi] = c;
        }
        if (t+1 < TT && tid < 256) {
            int b = tid >> 4, d = tid & 15;
            Af[b*AFS + HH + d] = x_d[((size_t)(B0+b)*TT + (t+1))*DD + d];
        }
        __syncthreads();   // Af (h and x) ready for step t+1
    }

    // ---- epilogue: out = h_T @ fc_w + fc_b ----
    if (tid < BB) {
        float a = fc_b[0];
        for (int k = 0; k < HH; ++k) a += Af[tid*AFS + k]*fc_w[k];
        out[B0 + tid] = a;
    }
}

extern "C" void kernel_launch(void* const* d_in, const int* in_sizes, int n_in,
                              void* d_out, int out_size, void* d_ws, size_t ws_size,
                              hipStream_t stream) {
    const float* x_d    = (const float*)d_in[0];
    const float* x_s    = (const float*)d_in[1];
    const float* w_ih   = (const float*)d_in[2];
    const float* w_hh   = (const float*)d_in[3];
    const float* w_sh   = (const float*)d_in[4];
    const float* bias   = (const float*)d_in[5];
    const float* bias_s = (const float*)d_in[6];
    const float* fc_w   = (const float*)d_in[7];
    const float* fc_b   = (const float*)d_in[8];

    float* out = (float*)d_out;
    float* h_n = out + BN;
    float* c_n = h_n + (size_t)BN * TT * HH;

    ealstm_f32<<<BN / BB, 512, 0, stream>>>(x_d, x_s, w_ih, w_hh, w_sh,
                                            bias, bias_s, fc_w, fc_b,
                                            out, h_n, c_n);
}

// Round 6
// 6628.587 us; speedup vs baseline: 2.2508x; 2.2508x over previous
//
#include <hip/hip_runtime.h>
#include <cstdint>

// EA-LSTM fused persistent kernel, split-fp16 MFMA edition.
// B=512 in 32 WGs x 16 rows; K = [h(256) | x_t(16) | pad(16)] = 288.
// Operands represented as fp16 hi+lo pairs; gates = A_hi*W_hi + A_hi*W_lo +
// A_lo*W_hi accumulated in f32 MFMA (fp16 products are exact -> ~f32-grade
// noise, required because the recurrence chaos-amplifies operand noise:
// measured f32->0.5, bf16->38 vs threshold 2.16).

#define BN   512
#define TT   365
#define DD   16
#define DSDIM 32
#define HH   256
#define G3   768
#define BB   16
#define NKC  9          // 9 k-chunks of 32 (256 h + 16 x + 16 zero-pad)
#define AS   296        // A row stride in halfs (288 + 8 pad)
#define WFRAG (48 * NKC * 64 * 8)   // halfs per weight copy (hi or lo)

typedef __attribute__((ext_vector_type(8))) _Float16 half8;
typedef __attribute__((ext_vector_type(4))) float f32x4;

static __device__ __forceinline__ float sigmoidf_(float x) {
    return 1.0f / (1.0f + __expf(-x));
}
static __device__ __forceinline__ float tanhf_(float x) {
    float e = __expf(2.0f * x);      // saturates correctly for large |x|
    return 1.0f - 2.0f / (e + 1.0f);
}

// Pack W_cat = [w_hh ; w_ih ; 0] (288 x 768) into MFMA-B fragment order,
// split into fp16 hi/lo:
// W[((nt*NKC+kc)*64+lane)*8+e] = W_cat[kc*32+(lane>>4)*8+e][nt*16+(lane&15)]
__global__ void pack_w(const float* __restrict__ w_ih, const float* __restrict__ w_hh,
                       _Float16* __restrict__ Whi, _Float16* __restrict__ Wlo) {
    int blk  = blockIdx.x;          // = nt*NKC + kc
    int kc   = blk % NKC;
    int nt   = blk / NKC;
    int lane = threadIdx.x;         // 64
    int n     = nt * 16 + (lane & 15);
    int kbase = kc * 32 + (lane >> 4) * 8;
    half8 vh, vl;
#pragma unroll
    for (int e = 0; e < 8; ++e) {
        int k = kbase + e;
        float f = 0.0f;
        if (k < HH)            f = w_hh[(size_t)k * G3 + n];
        else if (k < HH + DD)  f = w_ih[(size_t)(k - HH) * G3 + n];
        _Float16 hi = (_Float16)f;
        vh[e] = hi;
        vl[e] = (_Float16)(f - (float)hi);
    }
    size_t base = ((size_t)blk * 64 + lane) * 8;
    *(half8*)(Whi + base) = vh;
    *(half8*)(Wlo + base) = vl;
}

__global__ __launch_bounds__(512) void ealstm(
    const float* __restrict__ x_d, const float* __restrict__ x_s,
    const float* __restrict__ w_sh, const float* __restrict__ bias,
    const float* __restrict__ bias_s, const float* __restrict__ fc_w,
    const float* __restrict__ fc_b,
    const _Float16* __restrict__ Whi, const _Float16* __restrict__ Wlo,
    float* __restrict__ out, float* __restrict__ h_n, float* __restrict__ c_n)
{
    __shared__ _Float16 Ahi[BB * AS];       // [16 rows][288 k + pad]
    __shared__ _Float16 Alo[BB * AS];
    const int tid  = threadIdx.x;
    const int w    = tid >> 6;              // wave 0..7
    const int lane = tid & 63;
    const int col  = lane & 15;             // MFMA: A row / C col
    const int grp  = lane >> 4;             // MFMA: k-group / C row-group
    const int B0   = blockIdx.x * BB;

    // wave w owns j-slice [32w, 32w+32): n-tiles f:{2w,2w+1} o:{16+..} g:{32+..}
    int nt[6];
    nt[0] = 2*w;      nt[1] = 2*w + 1;
    nt[2] = 16 + 2*w; nt[3] = 16 + 2*w + 1;
    nt[4] = 32 + 2*w; nt[5] = 32 + 2*w + 1;

    float biasv[6];
#pragma unroll
    for (int u = 0; u < 6; ++u) biasv[u] = bias[nt[u] * 16 + col];

    // elementwise ownership (C-layout): b_loc = 4*grp+i, j = 32w + 16*u2 + col
    float c0[2][4], ig[2][4], hreg[2][4];
#pragma unroll
    for (int u2 = 0; u2 < 2; ++u2) {
        int j = 32*w + 16*u2 + col;
        for (int i = 0; i < 4; ++i) {
            int bg = B0 + 4*grp + i;
            float a = bias_s[j];
            for (int d = 0; d < DSDIM; ++d)
                a += x_s[bg * DSDIM + d] * w_sh[d * HH + j];
            ig[u2][i] = sigmoidf_(a);
            c0[u2][i] = 0.0f;
        }
    }

    // zero A (h=0, x and pad regions), then load x_0 (split hi/lo)
    for (int idx = tid; idx < BB * AS; idx += 512) { Ahi[idx] = (_Float16)0.f; Alo[idx] = (_Float16)0.f; }
    __syncthreads();
    if (tid < 256) {
        int bl = tid >> 4, d = tid & 15;
        float xv = x_d[((size_t)(B0 + bl) * TT + 0) * DD + d];
        _Float16 hi = (_Float16)xv;
        Ahi[bl * AS + HH + d] = hi;
        Alo[bl * AS + HH + d] = (_Float16)(xv - (float)hi);
    }
    __syncthreads();

    for (int t = 0; t < TT; ++t) {
        // ---- MFMA phase: gates = bias + [h|x] @ W_cat, split-fp16 ----
        f32x4 acc[6];
#pragma unroll
        for (int u = 0; u < 6; ++u)
            acc[u] = (f32x4){biasv[u], biasv[u], biasv[u], biasv[u]};
#pragma unroll
        for (int kc = 0; kc < NKC; ++kc) {
            half8 ah = *(const half8*)&Ahi[col * AS + kc * 32 + grp * 8];
            half8 al = *(const half8*)&Alo[col * AS + kc * 32 + grp * 8];
#pragma unroll
            for (int u = 0; u < 6; ++u) {
                size_t base = (((size_t)nt[u] * NKC + kc) * 64 + lane) * 8;
                half8 bh = *(const half8*)(Whi + base);
                half8 bl = *(const half8*)(Wlo + base);
                acc[u] = __builtin_amdgcn_mfma_f32_16x16x32_f16(ah, bh, acc[u], 0, 0, 0);
                acc[u] = __builtin_amdgcn_mfma_f32_16x16x32_f16(ah, bl, acc[u], 0, 0, 0);
                acc[u] = __builtin_amdgcn_mfma_f32_16x16x32_f16(al, bh, acc[u], 0, 0, 0);
            }
        }
        // ---- elementwise (pure registers): lane holds f,o,g for its 8 (b,j) ----
#pragma unroll
        for (int u2 = 0; u2 < 2; ++u2)
#pragma unroll
        for (int i = 0; i < 4; ++i) {
            float fg = sigmoidf_(acc[u2][i]);
            float og = sigmoidf_(acc[2 + u2][i]);
            float gg = tanhf_(acc[4 + u2][i]);
            float c  = fg * c0[u2][i] + ig[u2][i] * gg;
            c0[u2][i]   = c;
            hreg[u2][i] = og * tanhf_(c);
        }
        __syncthreads();   // all waves done reading A for step t
        // ---- write h(t) split hi/lo, and x(t+1), into A ----
#pragma unroll
        for (int u2 = 0; u2 < 2; ++u2)
#pragma unroll
        for (int i = 0; i < 4; ++i) {
            int bl = 4*grp + i;
            int j  = 32*w + 16*u2 + col;
            float hv = hreg[u2][i];
            _Float16 hi = (_Float16)hv;
            Ahi[bl * AS + j] = hi;
            Alo[bl * AS + j] = (_Float16)(hv - (float)hi);
        }
        if (t + 1 < TT && tid < 256) {
            int bl = tid >> 4, d = tid & 15;
            float xv = x_d[((size_t)(B0 + bl) * TT + (t + 1)) * DD + d];
            _Float16 hi = (_Float16)xv;
            Ahi[bl * AS + HH + d] = hi;
            Alo[bl * AS + HH + d] = (_Float16)(xv - (float)hi);
        }
        __syncthreads();   // A ready for step t+1
        // ---- global stores for step t ----
#pragma unroll
        for (int u2 = 0; u2 < 2; ++u2)
#pragma unroll
        for (int i = 0; i < 4; ++i) {
            int bg  = B0 + 4*grp + i;
            int j   = 32*w + 16*u2 + col;
            size_t idx = ((size_t)bg * TT + t) * HH + j;
            h_n[idx] = hreg[u2][i];
            c_n[idx] = c0[u2][i];
        }
    }

    // ---- epilogue: out[b] = h_T @ fc_w + fc_b ----
    if (tid < BB) {
        float a = fc_b[0];
        for (int k = 0; k < HH; ++k)
            a += ((float)Ahi[tid * AS + k] + (float)Alo[tid * AS + k]) * fc_w[k];
        out[B0 + tid] = a;
    }
}

extern "C" void kernel_launch(void* const* d_in, const int* in_sizes, int n_in,
                              void* d_out, int out_size, void* d_ws, size_t ws_size,
                              hipStream_t stream) {
    const float* x_d    = (const float*)d_in[0];
    const float* x_s    = (const float*)d_in[1];
    const float* w_ih   = (const float*)d_in[2];
    const float* w_hh   = (const float*)d_in[3];
    const float* w_sh   = (const float*)d_in[4];
    const float* bias   = (const float*)d_in[5];
    const float* bias_s = (const float*)d_in[6];
    const float* fc_w   = (const float*)d_in[7];
    const float* fc_b   = (const float*)d_in[8];

    float* out = (float*)d_out;
    float* h_n = out + BN;
    float* c_n = h_n + (size_t)BN * TT * HH;

    _Float16* Whi = (_Float16*)d_ws;        // 2 x 442368 B of fragment-packed weights
    _Float16* Wlo = Whi + WFRAG;

    pack_w<<<48 * NKC, 64, 0, stream>>>(w_ih, w_hh, Whi, Wlo);
    ealstm<<<BN / BB, 512, 0, stream>>>(x_d, x_s, w_sh, bias, bias_s, fc_w, fc_b,
                                        Whi, Wlo, out, h_n, c_n);
}